// Round 7
// baseline (66.719 us; speedup 1.0000x reference)
//
#include <hip/hip_runtime.h>

// AdaPT_Linear: per-tensor int8 quantized linear.
// out = (qx @ qw^T).f32 / (sa*sw) + qb.f32/sb
// x: [16384,1024] f32, w: [1024,1024] f32, b: [1024] f32, out: [16384,1024] f32

#define M_ROWS 16384
#define K_DIM  1024
#define N_OUT  1024

typedef int v4i __attribute__((ext_vector_type(4)));

__device__ __forceinline__ void gload_lds16(const void* g, void* l) {
  __builtin_amdgcn_global_load_lds(
      (const __attribute__((address_space(1))) void*)g,
      (__attribute__((address_space(3))) void*)l, 16, 0, 0);
}

__device__ __forceinline__ float block_reduce_max4(float m, float* red) {
#pragma unroll
  for (int off = 32; off > 0; off >>= 1)
    m = fmaxf(m, __shfl_down(m, off));
  const int wid = threadIdx.x >> 6, lane = threadIdx.x & 63;
  if (lane == 0) red[wid] = m;
  __syncthreads();
  float r = fmaxf(fmaxf(red[0], red[1]), fmaxf(red[2], red[3]));
  __syncthreads();
  return r;
}

__global__ void amax_stage1(const float* __restrict__ src, int n4,
                            float* __restrict__ partials) {
  __shared__ float red[4];
  float m = 0.0f;
  const int stride = gridDim.x * blockDim.x;
  for (int idx = blockIdx.x * blockDim.x + threadIdx.x; idx < n4; idx += stride) {
    float4 v = ((const float4*)src)[idx];
    m = fmaxf(m, fmaxf(fmaxf(fabsf(v.x), fabsf(v.y)), fmaxf(fabsf(v.z), fabsf(v.w))));
  }
  float r = block_reduce_max4(m, red);
  if (threadIdx.x == 0) partials[blockIdx.x] = r;
}

__global__ void finalize_kernel(const float* __restrict__ px, int npx,
                                const float* __restrict__ pw, int npw,
                                const float* __restrict__ bias,
                                float* __restrict__ amax,
                                float* __restrict__ bdeq) {
  __shared__ float red[4];
  const int tid = threadIdx.x;

  float m = 0.0f;
  for (int i = tid; i < npx; i += 256) m = fmaxf(m, px[i]);
  float rx = block_reduce_max4(m, red);

  m = 0.0f;
  for (int i = tid; i < npw; i += 256) m = fmaxf(m, pw[i]);
  float rw = block_reduce_max4(m, red);

  float4 bv = ((const float4*)bias)[tid];  // 256*4 == 1024 exactly
  m = fmaxf(fmaxf(fabsf(bv.x), fabsf(bv.y)), fmaxf(fabsf(bv.z), fabsf(bv.w)));
  float rb = block_reduce_max4(m, red);

  if (rx == 0.0f) rx = 1.0f;
  if (rw == 0.0f) rw = 1.0f;
  if (rb == 0.0f) rb = 1.0f;
  if (tid == 0) {
    amax[0] = rx;
    amax[1] = rw;
    amax[2] = rb;
  }
  const float sb = 127.0f / rb;
  float4 q;
  q.x = fminf(fmaxf(rintf(sb * bv.x), -127.0f), 127.0f) / sb;
  q.y = fminf(fmaxf(rintf(sb * bv.y), -127.0f), 127.0f) / sb;
  q.z = fminf(fmaxf(rintf(sb * bv.z), -127.0f), 127.0f) / sb;
  q.w = fminf(fmaxf(rintf(sb * bv.w), -127.0f), 127.0f) / sb;
  ((float4*)bdeq)[tid] = q;
}

__global__ void quant_kernel(const float* __restrict__ src, signed char* __restrict__ dst,
                             int n4, const float* __restrict__ amax, int slot) {
  const float s = 127.0f / amax[slot];
  const int stride = gridDim.x * blockDim.x;
  for (int idx = blockIdx.x * blockDim.x + threadIdx.x; idx < n4; idx += stride) {
    float4 v = ((const float4*)src)[idx];
    int q0 = (int)fminf(fmaxf(rintf(s * v.x), -127.0f), 127.0f);
    int q1 = (int)fminf(fmaxf(rintf(s * v.y), -127.0f), 127.0f);
    int q2 = (int)fminf(fmaxf(rintf(s * v.z), -127.0f), 127.0f);
    int q3 = (int)fminf(fmaxf(rintf(s * v.w), -127.0f), 127.0f);
    unsigned int packed = (q0 & 0xff) | ((q1 & 0xff) << 8) |
                          ((q2 & 0xff) << 16) | ((q3 & 0xff) << 24);
    ((unsigned int*)dst)[idx] = packed;
  }
}

// ---------------------------------------------------------------------------
// i8 GEMM, 256x128 tile, BK=64, 4 waves (2Mx2N, wave=128x64), double-buffered
// LDS 48KB -> TWO blocks per CU (96KB < 160KB): one block's barrier/vmcnt
// stalls and its end-of-kernel store burst overlap the other block's MFMA.
// Per iter: STAGE(next: 6 gloads/thread) -> VM(6) (current tile landed) ->
// barrier -> 12x ds_read_b128 frags + 32 MFMA -> lgkmcnt(0)+barrier (readers
// done before next iter's stager overwrites). 16 K-tiles.
// Swizzle (64B rows = 4 units): stored unit = globalunit ^ ((row>>1)&3),
// applied on pre-swizzled global source and on ds_read address (involution).
// Frag-read bank audit: lanes fr=0..15 map to (fr&1, q^((fr>>1)&3)) = 8
// distinct 4-bank groups x 2 lanes = conflict-free (2-way is free).
// ---------------------------------------------------------------------------
#define NKT 16

__global__ __launch_bounds__(256, 2) void gemm_kernel(
    const signed char* __restrict__ qx, const signed char* __restrict__ qw,
    const float* __restrict__ amax, const float* __restrict__ bdeq,
    float* __restrict__ out) {
  __shared__ char lds[49152];  // buf0: A 16K @0, B 8K @16384; buf1 @24576

  const int tid  = threadIdx.x;
  const int w    = tid >> 6;
  const int lane = tid & 63;
  const int wm = w >> 1;   // 0..1 (128 rows each)
  const int wn = w & 1;    // 0..1 (64 cols each)
  const int fr = lane & 15;
  const int q  = lane >> 4;

  // XCD-aware swizzle (grid 512 = 8 XCDs x 64 contiguous)
  const int bid = blockIdx.x;
  const int wg  = (bid & 7) * 64 + (bid >> 3);
  const int Mbase = (wg >> 3) * 256;
  const int Nbase = (wg & 7) * 128;

  const signed char* gA = qx + (size_t)Mbase * K_DIM;
  const signed char* gB = qw + (size_t)Nbase * K_DIM;

  // staging: thread t loads row (chunk*64 + (t>>2)), source unit (t&3)^((t>>3)&3)
  const int srow = tid >> 2;                       // 0..63 within chunk
  const int scol = ((tid & 3) ^ ((tid >> 3) & 3)) << 4;

  // fragment read: row R -> stored unit q ^ ((R>>1)&3) = q ^ ((fr>>1)&3)
  const int u0    = (q ^ ((fr >> 1) & 3)) << 4;
  const int aoffA = fr * 64 + u0;   // + f*16*64 within A half
  const int aoffB = fr * 64 + u0;   // + g*16*64

  const float inv_denom = (amax[0] * amax[1]) * (1.0f / 16129.0f);

  v4i acc[8][4] = {};
  v4i Ar[8], Br[4];

  // STAGE one K-tile into buffer BUF: A 4 chunks (64 rows), B 2 chunks
#define STG(BUF, T)                                                            \
  do {                                                                         \
    const int _k0 = (T)*64 + scol;                                             \
    char* _la = lds + (BUF)*24576;                                             \
    char* _lb = _la + 16384;                                                   \
    _Pragma("unroll") for (int i = 0; i < 4; ++i)                              \
      gload_lds16(gA + (size_t)(i * 64 + srow) * K_DIM + _k0,                  \
                  _la + i * 4096 + tid * 16);                                  \
    _Pragma("unroll") for (int i = 0; i < 2; ++i)                              \
      gload_lds16(gB + (size_t)(i * 64 + srow) * K_DIM + _k0,                  \
                  _lb + i * 4096 + tid * 16);                                  \
  } while (0)

#define VM(N) asm volatile("s_waitcnt vmcnt(" #N ")" ::: "memory")

  STG(0, 0);
  int cur = 0;
  for (int kt = 0; kt < NKT; ++kt) {
    if (kt + 1 < NKT) {
      STG(cur ^ 1, kt + 1);
      VM(6);           // the 6 just-issued remain; current tile fully landed
    } else {
      VM(0);
    }
    __builtin_amdgcn_s_barrier();

    const char* _A = lds + cur * 24576 + wm * 8192;   // 128 rows x 64B
    const char* _B = lds + cur * 24576 + 16384 + wn * 4096;  // 64 rows x 64B
#pragma unroll
    for (int f = 0; f < 8; ++f)
      Ar[f] = *(const v4i*)(_A + aoffA + f * 1024);
#pragma unroll
    for (int g = 0; g < 4; ++g)
      Br[g] = *(const v4i*)(_B + aoffB + g * 1024);
#pragma unroll
    for (int f = 0; f < 8; ++f)
#pragma unroll
      for (int g = 0; g < 4; ++g)
        acc[f][g] = __builtin_amdgcn_mfma_i32_16x16x64_i8(Ar[f], Br[g], acc[f][g], 0, 0, 0);

    asm volatile("s_waitcnt lgkmcnt(0)" ::: "memory");
    __builtin_amdgcn_s_barrier();
    cur ^= 1;
  }
#undef STG
#undef VM

  // epilogue: D frag col = fr, row = q*4 + i
#pragma unroll
  for (int f = 0; f < 8; ++f) {
    const int row0 = Mbase + wm * 128 + f * 16 + q * 4;
#pragma unroll
    for (int g = 0; g < 4; ++g) {
      const int col = Nbase + wn * 64 + g * 16 + fr;
      const float bb = bdeq[col];
#pragma unroll
      for (int i = 0; i < 4; ++i)
        out[(size_t)(row0 + i) * N_OUT + col] = (float)acc[f][g][i] * inv_denom + bb;
    }
  }
}

extern "C" void kernel_launch(void* const* d_in, const int* in_sizes, int n_in,
                              void* d_out, int out_size, void* d_ws, size_t ws_size,
                              hipStream_t stream) {
  const float* x = (const float*)d_in[0];
  const float* w = (const float*)d_in[1];
  const float* b = (const float*)d_in[2];
  float* out = (float*)d_out;

  char* ws = (char*)d_ws;
  float* amax = (float*)ws;                             // 3 floats
  float* bdeq = (float*)(ws + 256);                     // 4 KB
  float* px   = (float*)(ws + 8192);                    // 2048 partials
  float* pw   = (float*)(ws + 16384 + 8192);            // 256 partials
  signed char* qw = (signed char*)(ws + 65536);         // 1 MB
  signed char* qx = (signed char*)(ws + (1 << 21));     // 16 MB

  const int NPX = 2048, NPW = 256;
  hipLaunchKernelGGL(amax_stage1, dim3(NPX), dim3(256), 0, stream, x, M_ROWS * K_DIM / 4, px);
  hipLaunchKernelGGL(amax_stage1, dim3(NPW), dim3(256), 0, stream, w, N_OUT * K_DIM / 4, pw);
  hipLaunchKernelGGL(finalize_kernel, dim3(1), dim3(256), 0, stream, px, NPX, pw, NPW, b, amax, bdeq);
  hipLaunchKernelGGL(quant_kernel, dim3(2048), dim3(256), 0, stream, x, qx, M_ROWS * K_DIM / 4, amax, 0);
  hipLaunchKernelGGL(quant_kernel, dim3(256), dim3(256), 0, stream, w, qw, N_OUT * K_DIM / 4, amax, 1);
  hipLaunchKernelGGL(gemm_kernel, dim3(128 * 4), dim3(256), 0, stream, qx, qw, amax, bdeq, out);
}

// Round 9
// 65.531 us; speedup vs baseline: 1.0181x; 1.0181x over previous
//
#include <hip/hip_runtime.h>

// AdaPT_Linear: per-tensor int8 quantized linear.
// out = (qx @ qw^T).f32 / (sa*sw) + qb.f32/sb
// x: [16384,1024] f32, w: [1024,1024] f32, b: [1024] f32, out: [16384,1024] f32

#define M_ROWS 16384
#define K_DIM  1024
#define N_OUT  1024

typedef int v4i __attribute__((ext_vector_type(4)));
typedef float v4f __attribute__((ext_vector_type(4)));

__device__ __forceinline__ void gload_lds16(const void* g, void* l) {
  __builtin_amdgcn_global_load_lds(
      (const __attribute__((address_space(1))) void*)g,
      (__attribute__((address_space(3))) void*)l, 16, 0, 0);
}

__device__ __forceinline__ float block_reduce_max4(float m, float* red) {
#pragma unroll
  for (int off = 32; off > 0; off >>= 1)
    m = fmaxf(m, __shfl_down(m, off));
  const int wid = threadIdx.x >> 6, lane = threadIdx.x & 63;
  if (lane == 0) red[wid] = m;
  __syncthreads();
  float r = fmaxf(fmaxf(red[0], red[1]), fmaxf(red[2], red[3]));
  __syncthreads();
  return r;
}

__global__ void amax_stage1(const float* __restrict__ src, int n4,
                            float* __restrict__ partials) {
  __shared__ float red[4];
  float m = 0.0f;
  const int stride = gridDim.x * blockDim.x;
  for (int idx = blockIdx.x * blockDim.x + threadIdx.x; idx < n4; idx += stride) {
    float4 v = ((const float4*)src)[idx];
    m = fmaxf(m, fmaxf(fmaxf(fabsf(v.x), fabsf(v.y)), fmaxf(fabsf(v.z), fabsf(v.w))));
  }
  float r = block_reduce_max4(m, red);
  if (threadIdx.x == 0) partials[blockIdx.x] = r;
}

__global__ void finalize_kernel(const float* __restrict__ px, int npx,
                                const float* __restrict__ pw, int npw,
                                const float* __restrict__ bias,
                                float* __restrict__ amax,
                                float* __restrict__ bdeq) {
  __shared__ float red[4];
  const int tid = threadIdx.x;

  float m = 0.0f;
  for (int i = tid; i < npx; i += 256) m = fmaxf(m, px[i]);
  float rx = block_reduce_max4(m, red);

  m = 0.0f;
  for (int i = tid; i < npw; i += 256) m = fmaxf(m, pw[i]);
  float rw = block_reduce_max4(m, red);

  float4 bv = ((const float4*)bias)[tid];  // 256*4 == 1024 exactly
  m = fmaxf(fmaxf(fabsf(bv.x), fabsf(bv.y)), fmaxf(fabsf(bv.z), fabsf(bv.w)));
  float rb = block_reduce_max4(m, red);

  if (rx == 0.0f) rx = 1.0f;
  if (rw == 0.0f) rw = 1.0f;
  if (rb == 0.0f) rb = 1.0f;
  if (tid == 0) {
    amax[0] = rx;
    amax[1] = rw;
    amax[2] = rb;
  }
  const float sb = 127.0f / rb;
  float4 q;
  q.x = fminf(fmaxf(rintf(sb * bv.x), -127.0f), 127.0f) / sb;
  q.y = fminf(fmaxf(rintf(sb * bv.y), -127.0f), 127.0f) / sb;
  q.z = fminf(fmaxf(rintf(sb * bv.z), -127.0f), 127.0f) / sb;
  q.w = fminf(fmaxf(rintf(sb * bv.w), -127.0f), 127.0f) / sb;
  ((float4*)bdeq)[tid] = q;
}

__global__ void quant_kernel(const float* __restrict__ src, signed char* __restrict__ dst,
                             int n4, const float* __restrict__ amax, int slot) {
  const float s = 127.0f / amax[slot];
  const int stride = gridDim.x * blockDim.x;
  for (int idx = blockIdx.x * blockDim.x + threadIdx.x; idx < n4; idx += stride) {
    float4 v = ((const float4*)src)[idx];
    int q0 = (int)fminf(fmaxf(rintf(s * v.x), -127.0f), 127.0f);
    int q1 = (int)fminf(fmaxf(rintf(s * v.y), -127.0f), 127.0f);
    int q2 = (int)fminf(fmaxf(rintf(s * v.z), -127.0f), 127.0f);
    int q3 = (int)fminf(fmaxf(rintf(s * v.w), -127.0f), 127.0f);
    unsigned int packed = (q0 & 0xff) | ((q1 & 0xff) << 8) |
                          ((q2 & 0xff) << 16) | ((q3 & 0xff) << 24);
    ((unsigned int*)dst)[idx] = packed;
  }
}

// ---------------------------------------------------------------------------
// i8 GEMM, 256x128 tile, BK=64, 4 waves (2Mx2N, wave=128x64), dbuf LDS 48KB,
// 2 blocks/CU. K-loop identical to R7 (it was not the limiter). NEW: the
// epilogue — forensics showed gemm is STORE-PATH bound (WRITE 70MB @1.7TB/s,
// 128 scalar dword stores/thread, 64B segments, L2 write-allocate thrash).
// Now: apply scale+bias in-frag, LDS-transpose each 16x64 f-chunk (stride-66
// pad: 2-way banks = free), read back row-major, store as NONTEMPORAL v4f
// (16 lanes x 16B = 256B contiguous per quarter-wave; nt bypasses L2 so qx
// stays resident). 32 wide stores/thread vs 128 scalar.
// Swizzle (64B rows = 4 units): stored unit = globalunit ^ ((row>>1)&3) on
// pre-swizzled source + ds_read address (involution). Frag-read conflict-free
// (8 groups x 2 lanes). Per-wave epilogue LDS region is private (12KB each);
// one barrier after K-loop, then wave-local lgkmcnt ordering only.
// ---------------------------------------------------------------------------
#define NKT 16

__global__ __launch_bounds__(256, 2) void gemm_kernel(
    const signed char* __restrict__ qx, const signed char* __restrict__ qw,
    const float* __restrict__ amax, const float* __restrict__ bdeq,
    float* __restrict__ out) {
  __shared__ char lds[49152];  // buf0: A 16K @0, B 8K @16384; buf1 @24576

  const int tid  = threadIdx.x;
  const int w    = tid >> 6;
  const int lane = tid & 63;
  const int wm = w >> 1;   // 0..1 (128 rows each)
  const int wn = w & 1;    // 0..1 (64 cols each)
  const int fr = lane & 15;
  const int q  = lane >> 4;

  // XCD-aware swizzle (grid 512 = 8 XCDs x 64 contiguous)
  const int bid = blockIdx.x;
  const int wg  = (bid & 7) * 64 + (bid >> 3);
  const int Mbase = (wg >> 3) * 256;
  const int Nbase = (wg & 7) * 128;

  const signed char* gA = qx + (size_t)Mbase * K_DIM;
  const signed char* gB = qw + (size_t)Nbase * K_DIM;

  // staging: thread t loads row (chunk*64 + (t>>2)), source unit (t&3)^((t>>3)&3)
  const int srow = tid >> 2;                       // 0..63 within chunk
  const int scol = ((tid & 3) ^ ((tid >> 3) & 3)) << 4;

  // fragment read: row R -> stored unit q ^ ((R>>1)&3) = q ^ ((fr>>1)&3)
  const int u0    = (q ^ ((fr >> 1) & 3)) << 4;
  const int aoffA = fr * 64 + u0;   // + f*16*64 within A half
  const int aoffB = fr * 64 + u0;   // + g*16*64

  const float inv_denom = (amax[0] * amax[1]) * (1.0f / 16129.0f);
  // bias per acc column (pre-transpose): col = Nbase + wn*64 + g*16 + fr
  float bdq[4];
#pragma unroll
  for (int g = 0; g < 4; ++g) bdq[g] = bdeq[Nbase + wn * 64 + g * 16 + fr];

  v4i acc[8][4] = {};
  v4i Ar[8], Br[4];

#define STG(BUF, T)                                                            \
  do {                                                                         \
    const int _k0 = (T)*64 + scol;                                             \
    char* _la = lds + (BUF)*24576;                                             \
    char* _lb = _la + 16384;                                                   \
    _Pragma("unroll") for (int i = 0; i < 4; ++i)                              \
      gload_lds16(gA + (size_t)(i * 64 + srow) * K_DIM + _k0,                  \
                  _la + i * 4096 + tid * 16);                                  \
    _Pragma("unroll") for (int i = 0; i < 2; ++i)                              \
      gload_lds16(gB + (size_t)(i * 64 + srow) * K_DIM + _k0,                  \
                  _lb + i * 4096 + tid * 16);                                  \
  } while (0)

#define VM(N) asm volatile("s_waitcnt vmcnt(" #N ")" ::: "memory")

  STG(0, 0);
  int cur = 0;
  for (int kt = 0; kt < NKT; ++kt) {
    if (kt + 1 < NKT) {
      STG(cur ^ 1, kt + 1);
      VM(6);           // the 6 just-issued remain; current tile fully landed
    } else {
      VM(0);
    }
    __builtin_amdgcn_s_barrier();

    const char* _A = lds + cur * 24576 + wm * 8192;          // 128 rows x 64B
    const char* _B = lds + cur * 24576 + 16384 + wn * 4096;  // 64 rows x 64B
#pragma unroll
    for (int f = 0; f < 8; ++f)
      Ar[f] = *(const v4i*)(_A + aoffA + f * 1024);
#pragma unroll
    for (int g = 0; g < 4; ++g)
      Br[g] = *(const v4i*)(_B + aoffB + g * 1024);
#pragma unroll
    for (int f = 0; f < 8; ++f)
#pragma unroll
      for (int g = 0; g < 4; ++g)
        acc[f][g] = __builtin_amdgcn_mfma_i32_16x16x64_i8(Ar[f], Br[g], acc[f][g], 0, 0, 0);

    asm volatile("s_waitcnt lgkmcnt(0)" ::: "memory");
    __builtin_amdgcn_s_barrier();
    cur ^= 1;
  }
#undef STG
#undef VM

  // ------------------------ epilogue (store-path) --------------------------
  __syncthreads();  // staging LDS dead; safe to repurpose

  // per-wave private 16x64 f32 chunk buffer, row stride 66 (pad: 2-way banks)
  float* lws = (float*)(lds + w * 12288);  // 16*66*4 = 4224 B used of 12 KB

  const int erow = lane >> 4;   // 0..3 (base row within 16-row chunk)
  const int ecg  = lane & 15;   // col group: 4 cols each
  float* const orow_base = out + (size_t)(Mbase + wm * 128) * N_OUT +
                           (Nbase + wn * 64) + ecg * 4;

#pragma unroll
  for (int f = 0; f < 8; ++f) {
    // scatter scaled acc into LDS: [row16 = q*4+i][col = g*16+fr]
#pragma unroll
    for (int g = 0; g < 4; ++g)
#pragma unroll
      for (int i = 0; i < 4; ++i)
        lws[(q * 4 + i) * 66 + g * 16 + fr] =
            (float)acc[f][g][i] * inv_denom + bdq[g];
    asm volatile("s_waitcnt lgkmcnt(0)" ::: "memory");  // wave-local ordering
    // gather row-major, store 256B-contiguous nontemporal v4f
#pragma unroll
    for (int t = 0; t < 4; ++t) {
      const int r16 = t * 4 + erow;
      v4f v = *(const v4f*)&lws[r16 * 66 + ecg * 4];
      __builtin_nontemporal_store(
          v, (v4f*)(orow_base + (size_t)(f * 16 + r16) * N_OUT));
    }
    asm volatile("s_waitcnt lgkmcnt(0)" ::: "memory");  // reads done before overwrite
  }
}

extern "C" void kernel_launch(void* const* d_in, const int* in_sizes, int n_in,
                              void* d_out, int out_size, void* d_ws, size_t ws_size,
                              hipStream_t stream) {
  const float* x = (const float*)d_in[0];
  const float* w = (const float*)d_in[1];
  const float* b = (const float*)d_in[2];
  float* out = (float*)d_out;

  char* ws = (char*)d_ws;
  float* amax = (float*)ws;                             // 3 floats
  float* bdeq = (float*)(ws + 256);                     // 4 KB
  float* px   = (float*)(ws + 8192);                    // 2048 partials
  float* pw   = (float*)(ws + 16384 + 8192);            // 256 partials
  signed char* qw = (signed char*)(ws + 65536);         // 1 MB
  signed char* qx = (signed char*)(ws + (1 << 21));     // 16 MB

  const int NPX = 2048, NPW = 256;
  hipLaunchKernelGGL(amax_stage1, dim3(NPX), dim3(256), 0, stream, x, M_ROWS * K_DIM / 4, px);
  hipLaunchKernelGGL(amax_stage1, dim3(NPW), dim3(256), 0, stream, w, N_OUT * K_DIM / 4, pw);
  hipLaunchKernelGGL(finalize_kernel, dim3(1), dim3(256), 0, stream, px, NPX, pw, NPW, b, amax, bdeq);
  hipLaunchKernelGGL(quant_kernel, dim3(2048), dim3(256), 0, stream, x, qx, M_ROWS * K_DIM / 4, amax, 0);
  hipLaunchKernelGGL(quant_kernel, dim3(256), dim3(256), 0, stream, w, qw, N_OUT * K_DIM / 4, amax, 1);
  hipLaunchKernelGGL(gemm_kernel, dim3(128 * 4), dim3(256), 0, stream, qx, qw, amax, bdeq, out);
}

// Round 10
// 64.541 us; speedup vs baseline: 1.0337x; 1.0153x over previous
//
#include <hip/hip_runtime.h>

// AdaPT_Linear: per-tensor int8 quantized linear.
// out = (qx @ qw^T).f32 / (sa*sw) + qb.f32/sb
// x: [16384,1024] f32, w: [1024,1024] f32, b: [1024] f32, out: [16384,1024] f32

#define M_ROWS 16384
#define K_DIM  1024
#define N_OUT  1024

typedef int v4i __attribute__((ext_vector_type(4)));
typedef float v4f __attribute__((ext_vector_type(4)));

__device__ __forceinline__ void gload_lds16(const void* g, void* l) {
  __builtin_amdgcn_global_load_lds(
      (const __attribute__((address_space(1))) void*)g,
      (__attribute__((address_space(3))) void*)l, 16, 0, 0);
}

__device__ __forceinline__ float block_reduce_max4(float m, float* red) {
#pragma unroll
  for (int off = 32; off > 0; off >>= 1)
    m = fmaxf(m, __shfl_down(m, off));
  const int wid = threadIdx.x >> 6, lane = threadIdx.x & 63;
  if (lane == 0) red[wid] = m;
  __syncthreads();
  float r = fmaxf(fmaxf(red[0], red[1]), fmaxf(red[2], red[3]));
  __syncthreads();
  return r;
}

__global__ void amax_stage1(const float* __restrict__ src, int n4,
                            float* __restrict__ partials) {
  __shared__ float red[4];
  float m = 0.0f;
  const int stride = gridDim.x * blockDim.x;
  for (int idx = blockIdx.x * blockDim.x + threadIdx.x; idx < n4; idx += stride) {
    float4 v = ((const float4*)src)[idx];
    m = fmaxf(m, fmaxf(fmaxf(fabsf(v.x), fabsf(v.y)), fmaxf(fabsf(v.z), fabsf(v.w))));
  }
  float r = block_reduce_max4(m, red);
  if (threadIdx.x == 0) partials[blockIdx.x] = r;
}

__global__ void finalize_kernel(const float* __restrict__ px, int npx,
                                const float* __restrict__ pw, int npw,
                                const float* __restrict__ bias,
                                float* __restrict__ amax,
                                float* __restrict__ bdeq) {
  __shared__ float red[4];
  const int tid = threadIdx.x;

  float m = 0.0f;
  for (int i = tid; i < npx; i += 256) m = fmaxf(m, px[i]);
  float rx = block_reduce_max4(m, red);

  m = 0.0f;
  for (int i = tid; i < npw; i += 256) m = fmaxf(m, pw[i]);
  float rw = block_reduce_max4(m, red);

  float4 bv = ((const float4*)bias)[tid];  // 256*4 == 1024 exactly
  m = fmaxf(fmaxf(fabsf(bv.x), fabsf(bv.y)), fmaxf(fabsf(bv.z), fabsf(bv.w)));
  float rb = block_reduce_max4(m, red);

  if (rx == 0.0f) rx = 1.0f;
  if (rw == 0.0f) rw = 1.0f;
  if (rb == 0.0f) rb = 1.0f;
  if (tid == 0) {
    amax[0] = rx;
    amax[1] = rw;
    amax[2] = rb;
  }
  const float sb = 127.0f / rb;
  float4 q;
  q.x = fminf(fmaxf(rintf(sb * bv.x), -127.0f), 127.0f) / sb;
  q.y = fminf(fmaxf(rintf(sb * bv.y), -127.0f), 127.0f) / sb;
  q.z = fminf(fmaxf(rintf(sb * bv.z), -127.0f), 127.0f) / sb;
  q.w = fminf(fmaxf(rintf(sb * bv.w), -127.0f), 127.0f) / sb;
  ((float4*)bdeq)[tid] = q;
}

__global__ void quant_kernel(const float* __restrict__ src, signed char* __restrict__ dst,
                             int n4, const float* __restrict__ amax, int slot) {
  const float s = 127.0f / amax[slot];
  const int stride = gridDim.x * blockDim.x;
  for (int idx = blockIdx.x * blockDim.x + threadIdx.x; idx < n4; idx += stride) {
    float4 v = ((const float4*)src)[idx];
    int q0 = (int)fminf(fmaxf(rintf(s * v.x), -127.0f), 127.0f);
    int q1 = (int)fminf(fmaxf(rintf(s * v.y), -127.0f), 127.0f);
    int q2 = (int)fminf(fmaxf(rintf(s * v.z), -127.0f), 127.0f);
    int q3 = (int)fminf(fmaxf(rintf(s * v.w), -127.0f), 127.0f);
    unsigned int packed = (q0 & 0xff) | ((q1 & 0xff) << 8) |
                          ((q2 & 0xff) << 16) | ((q3 & 0xff) << 24);
    ((unsigned int*)dst)[idx] = packed;
  }
}

// ---------------------------------------------------------------------------
// i8 GEMM, 256x128 tile, BK=64, 4 waves (2Mx2N, wave=128x64), dbuf 48KB,
// 2 blocks/CU, faithful m201-style 8-PHASE schedule (T2+T3+T4+T5 combo):
// per phase {reg-persistent subtile ds_read || ~1 half-tile stage -> BAR ->
// lgkmcnt(0) -> setprio(1) -> 8 MFMA (one 64x32 quadrant, K=64) -> setprio(0)
// -> BAR}, counted vmcnt ONLY at ph4/ph8. Quadrant order (0,0),(0,1),(1,1),
// (1,0); A-quad read ph1/ph3 (4 rd), B-halves ph1/ph2 (2 rd each, both live).
// Stage-half slots: A-h(wm) last read ph3(buf0)/ph7(buf1); B-h(wn) ph2/ph6.
// Stage ledger/iter j (buf0=t2j, buf1=t2j+1; t2=2j+2, t3=2j+3, &15 dummies):
//  ph1:A1h1<-t(2j+1)[2] ph3:B0h0<-t2[1] ph4:B0h1<-t2[1] ph5:A0h0<-t2[2]
//  ph6:A0h1<-t2[2] ph7:B1h0<-t3[1] ph8:B1h1<-t3[1]+A1h0<-t3[2]  (12 loads)
// vmcnt audit (oldest-first): ph4: [p7(1),p8(3),c1(2),c3(1),c4(1)]=8 ->
// VM(2) drains buf1-tile complete (deadlines ph5-8). ph8: [c3,c4,c5,c6(6),
// c7(1),c8(3)]=10 -> VM(4) drains buf0-next-tile (deadline next ph1).
// Prologue: t0 full (6) + t1 minus A-h1 (4), VM(4) -> t0 landed; steady ok.
// Tail: dummy stages keep ledger; VM(0)+bar before LDS repurpose (epilogue).
// Swizzle: stored unit = globalunit ^ ((row>>1)&3) via pre-swizzled source +
// swizzled ds_read (involution). Epilogue: R9 LDS-transpose + nt v4f stores.
// ---------------------------------------------------------------------------
#define NKT 16

__global__ __launch_bounds__(256, 2) void gemm_kernel(
    const signed char* __restrict__ qx, const signed char* __restrict__ qw,
    const float* __restrict__ amax, const float* __restrict__ bdeq,
    float* __restrict__ out) {
  __shared__ char lds[49152];  // per buf: A 16K, B 8K; buf stride 24576

  const int tid  = threadIdx.x;
  const int w    = tid >> 6;
  const int lane = tid & 63;
  const int wm = w >> 1;   // 0..1 (128 rows)
  const int wn = w & 1;    // 0..1 (64 cols)
  const int fr = lane & 15;
  const int q  = lane >> 4;

  // XCD-aware swizzle (grid 512 = 8 XCDs x 64 contiguous)
  const int bid = blockIdx.x;
  const int wg  = (bid & 7) * 64 + (bid >> 3);
  const int Mbase = (wg >> 3) * 256;
  const int Nbase = (wg & 7) * 128;

  const signed char* gA = qx + (size_t)Mbase * K_DIM;
  const signed char* gB = qw + (size_t)Nbase * K_DIM;

  const int scol = ((tid & 3) ^ ((tid >> 3) & 3)) << 4;  // pre-swizzled src unit
  const int u0b  = (q ^ ((fr >> 1) & 3)) << 4;           // swizzled read unit

  const float inv_denom = (amax[0] * amax[1]) * (1.0f / 16129.0f);

  v4i acc[8][4] = {};
  v4i Ar[4];        // current A-quadrant frags
  v4i Br[2][2];     // both B-halves [NH][g'] (live across phases)

  // A-half H (128 rows, 8KB): 2 gloads/thread. B-half H (64 rows, 4KB): 1.
#define STG_A(BUF, H, T)                                                       \
  do {                                                                         \
    const int _k0 = (T)*64 + scol;                                             \
    char* _l = lds + (BUF)*24576 + (H)*8192 + tid * 16;                        \
    const signed char* _g = gA + (size_t)((H)*128 + (tid >> 2)) * K_DIM + _k0; \
    gload_lds16(_g, _l);                                                       \
    gload_lds16(_g + (size_t)64 * K_DIM, _l + 4096);                           \
  } while (0)

#define STG_B(BUF, H, T)                                                       \
  do {                                                                         \
    const int _k0 = (T)*64 + scol;                                             \
    gload_lds16(gB + (size_t)((H)*64 + (tid >> 2)) * K_DIM + _k0,              \
                lds + (BUF)*24576 + 16384 + (H)*4096 + tid * 16);              \
  } while (0)

#define RD_A(BUF, MH)                                                          \
  do {                                                                         \
    const char* _A = lds + (BUF)*24576 + wm * 8192 + (MH)*4096;                \
    _Pragma("unroll") for (int f = 0; f < 4; ++f)                              \
        Ar[f] = *(const v4i*)(_A + f * 1024 + fr * 64 + u0b);                  \
  } while (0)

#define RD_B(BUF, NH)                                                          \
  do {                                                                         \
    const char* _B = lds + (BUF)*24576 + 16384 + wn * 4096 + (NH)*2048;        \
    _Pragma("unroll") for (int g = 0; g < 2; ++g)                              \
        Br[NH][g] = *(const v4i*)(_B + g * 1024 + fr * 64 + u0b);              \
  } while (0)

#define MFMA_Q(MH, NH)                                                         \
  do {                                                                         \
    __builtin_amdgcn_s_setprio(1);                                             \
    _Pragma("unroll") for (int f = 0; f < 4; ++f)                              \
      _Pragma("unroll") for (int g = 0; g < 2; ++g)                            \
          acc[(MH)*4 + f][(NH)*2 + g] = __builtin_amdgcn_mfma_i32_16x16x64_i8( \
              Ar[f], Br[NH][g], acc[(MH)*4 + f][(NH)*2 + g], 0, 0, 0);         \
    __builtin_amdgcn_s_setprio(0);                                             \
  } while (0)

#define VM(N) asm volatile("s_waitcnt vmcnt(" #N ")" ::: "memory")
#define LGKM0() asm volatile("s_waitcnt lgkmcnt(0)" ::: "memory")
#define BAR() __builtin_amdgcn_s_barrier()

  // prologue: t0 full (B0h0,B0h1,A0h0,A0h1 = 6 loads); t1 minus A-h1 (4)
  STG_B(0, 0, 0); STG_B(0, 1, 0); STG_A(0, 0, 0); STG_A(0, 1, 0);
  STG_B(1, 0, 1); STG_B(1, 1, 1); STG_A(1, 0, 1);
  VM(4);  // t0 fully landed
  BAR();

  for (int j = 0; j < 8; ++j) {
    const int tb1 = (2 * j + 1) & 15;  // buf1 tile (A-h1 deferred stage)
    const int t2  = (2 * j + 2) & 15;  // j=7: dummy re-stages (consumed by none)
    const int t3  = (2 * j + 3) & 15;
    // ---- buf0 ----
    RD_A(0, 0); RD_B(0, 0); STG_A(1, 1, tb1);
    BAR(); LGKM0(); MFMA_Q(0, 0); BAR();                 // ph1
    RD_B(0, 1);
    BAR(); LGKM0(); MFMA_Q(0, 1); BAR();                 // ph2
    RD_A(0, 1); STG_B(0, 0, t2);
    BAR(); LGKM0(); MFMA_Q(1, 1); BAR();                 // ph3
    STG_B(0, 1, t2);
    BAR(); MFMA_Q(1, 0); VM(2); BAR();                   // ph4
    // ---- buf1 ----
    RD_A(1, 0); RD_B(1, 0); STG_A(0, 0, t2);
    BAR(); LGKM0(); MFMA_Q(0, 0); BAR();                 // ph5
    RD_B(1, 1); STG_A(0, 1, t2);
    BAR(); LGKM0(); MFMA_Q(0, 1); BAR();                 // ph6
    RD_A(1, 1); STG_B(1, 0, t3);
    BAR(); LGKM0(); MFMA_Q(1, 1); BAR();                 // ph7
    STG_B(1, 1, t3); STG_A(1, 0, t3);
    BAR(); MFMA_Q(1, 0); VM(4); BAR();                   // ph8
  }
#undef STG_A
#undef STG_B
#undef RD_A
#undef RD_B
#undef MFMA_Q

  // ------------------------ epilogue (store-path) --------------------------
  VM(0);           // dummy stages done writing LDS
  __syncthreads(); // staging LDS dead; repurpose

  const float bdq0 = bdeq[Nbase + wn * 64 + fr];        // g=0: col +0
  const float bdq1 = bdeq[Nbase + wn * 64 + 16 + fr];   // g=1
  const float bdq2 = bdeq[Nbase + wn * 64 + 32 + fr];   // g=2
  const float bdq3 = bdeq[Nbase + wn * 64 + 48 + fr];   // g=3
  const float bdq[4] = {bdq0, bdq1, bdq2, bdq3};

  float* lws = (float*)(lds + w * 8192);  // 16x66 f32 = 4224B of 8KB/wave

  const int erow = lane >> 4;
  const int ecg  = lane & 15;
  float* const orow_base = out + (size_t)(Mbase + wm * 128) * N_OUT +
                           (Nbase + wn * 64) + ecg * 4;

#pragma unroll
  for (int f = 0; f < 8; ++f) {
    // acc[f] covers rows (f>>2)*64 + (f&3)*16; cols (g>>1)*32 + (g&1)*16 + fr
#pragma unroll
    for (int g = 0; g < 4; ++g) {
      const int lc = (g >> 1) * 32 + (g & 1) * 16 + fr;
#pragma unroll
      for (int i = 0; i < 4; ++i)
        lws[(q * 4 + i) * 66 + lc] = (float)acc[f][g][i] * inv_denom + bdq[g];
    }
    LGKM0();  // wave-local ordering
#pragma unroll
    for (int t = 0; t < 4; ++t) {
      const int r16 = t * 4 + erow;
      v4f v = *(const v4f*)&lws[r16 * 66 + ecg * 4];
      const int row = (f >> 2) * 64 + (f & 3) * 16 + r16;
      __builtin_nontemporal_store(v, (v4f*)(orow_base + (size_t)row * N_OUT));
    }
    LGKM0();  // reads done before next overwrite
  }
#undef VM
#undef LGKM0
#undef BAR
}

extern "C" void kernel_launch(void* const* d_in, const int* in_sizes, int n_in,
                              void* d_out, int out_size, void* d_ws, size_t ws_size,
                              hipStream_t stream) {
  const float* x = (const float*)d_in[0];
  const float* w = (const float*)d_in[1];
  const float* b = (const float*)d_in[2];
  float* out = (float*)d_out;

  char* ws = (char*)d_ws;
  float* amax = (float*)ws;                             // 3 floats
  float* bdeq = (float*)(ws + 256);                     // 4 KB
  float* px   = (float*)(ws + 8192);                    // 2048 partials
  float* pw   = (float*)(ws + 16384 + 8192);            // 256 partials
  signed char* qw = (signed char*)(ws + 65536);         // 1 MB
  signed char* qx = (signed char*)(ws + (1 << 21));     // 16 MB

  const int NPX = 2048, NPW = 256;
  hipLaunchKernelGGL(amax_stage1, dim3(NPX), dim3(256), 0, stream, x, M_ROWS * K_DIM / 4, px);
  hipLaunchKernelGGL(amax_stage1, dim3(NPW), dim3(256), 0, stream, w, N_OUT * K_DIM / 4, pw);
  hipLaunchKernelGGL(finalize_kernel, dim3(1), dim3(256), 0, stream, px, NPX, pw, NPW, b, amax, bdeq);
  hipLaunchKernelGGL(quant_kernel, dim3(2048), dim3(256), 0, stream, x, qx, M_ROWS * K_DIM / 4, amax, 0);
  hipLaunchKernelGGL(quant_kernel, dim3(256), dim3(256), 0, stream, w, qw, N_OUT * K_DIM / 4, amax, 1);
  hipLaunchKernelGGL(gemm_kernel, dim3(128 * 4), dim3(256), 0, stream, qx, qw, amax, bdeq, out);
}